// Round 8
// baseline (826.533 us; speedup 1.0000x reference)
//
#include <hip/hip_runtime.h>
#include <hip/hip_bf16.h>

typedef __hip_bfloat16 bf16;
typedef short bf16x8 __attribute__((ext_vector_type(8)));
typedef float f32x4 __attribute__((ext_vector_type(4)));

__device__ __forceinline__ unsigned short f2bf(float f){
  __hip_bfloat16 h = __float2bfloat16(f);
  unsigned short u; __builtin_memcpy(&u, &h, 2); return u;
}

__device__ __forceinline__ void gload_lds16(const void* g, void* l){
  __builtin_amdgcn_global_load_lds((const __attribute__((address_space(1))) unsigned int*)g,
                                   (__attribute__((address_space(3))) unsigned int*)l, 16, 0, 0);
}

// fast GELU: x*sigmoid(1.59577(x+0.044715x^3)) == tanh-approx GELU; |err| ~1e-3 << bf16 ulp of act
__device__ __forceinline__ float fast_gelu(float x){
  float t = 1.5957691216f * x * (1.f + 0.044715f * x * x);
  return x / (1.f + __expf(-t));
}

// ---------------- weight packing (fp32 -> bf16, transposed to B^T layout) ----------------

__global__ __launch_bounds__(256) void packT_kernel(const float* __restrict__ in, bf16* __restrict__ out, int R, int C){
  __shared__ float tile[32][33];
  const int tid = threadIdx.x;
  const int tc = tid & 31, tr = tid >> 5;
  const int r0 = blockIdx.y * 32, c0 = blockIdx.x * 32;
  #pragma unroll
  for (int i=0;i<4;i++)
    tile[tr + i*8][tc] = in[(size_t)(r0 + tr + i*8)*C + c0 + tc];
  __syncthreads();
  #pragma unroll
  for (int i=0;i<4;i++){
    int oc = tr + i*8;
    out[(size_t)(c0 + oc)*R + r0 + tc] = __float2bfloat16(tile[tc][oc]);
  }
}

// fc_w (8,1024,4096) -> WfcT (32768,1024); row c = e*4096 + cl(j),
// cl(j) = ((j&2047)>>4)*32 + (j>>11)*16 + (j&15)
__global__ __launch_bounds__(256) void pack_fc_kernel(const float* __restrict__ fcw, bf16* __restrict__ out){
  __shared__ float tile[32][33];
  const int tid = threadIdx.x;
  const int tc = tid & 31, tr = tid >> 5;
  const int e = blockIdx.z;
  const int d0 = blockIdx.y * 32, j0 = blockIdx.x * 32;
  #pragma unroll
  for (int i=0;i<4;i++)
    tile[tr + i*8][tc] = fcw[((size_t)e*1024 + d0 + tr + i*8)*4096 + j0 + tc];
  __syncthreads();
  #pragma unroll
  for (int i=0;i<4;i++){
    int j = j0 + tr + i*8;
    int cl = ((j & 2047) >> 4)*32 + (j >> 11)*16 + (j & 15);
    out[((size_t)e*4096 + cl)*1024 + d0 + tc] = __float2bfloat16(tile[tc][tr + i*8]);
  }
}

// eout_w (8,2048,1024) -> WeoutT (1024,16384): out[d][e*2048+f] = in[e][f][d]
__global__ __launch_bounds__(256) void pack_eout_kernel(const float* __restrict__ eow, bf16* __restrict__ out){
  __shared__ float tile[32][33];
  const int tid = threadIdx.x;
  const int tc = tid & 31, tr = tid >> 5;
  const int e = blockIdx.z;
  const int d0 = blockIdx.y * 32, f0 = blockIdx.x * 32;
  #pragma unroll
  for (int i=0;i<4;i++)
    tile[tr + i*8][tc] = eow[((size_t)e*2048 + f0 + tr + i*8)*1024 + d0 + tc];
  __syncthreads();
  #pragma unroll
  for (int i=0;i<4;i++){
    int d = d0 + tr + i*8;
    out[(size_t)d*16384 + e*2048 + f0 + tc] = __float2bfloat16(tile[tc][tr + i*8]);
  }
}

__global__ __launch_bounds__(256) void pack_biasfc_kernel(const float* __restrict__ fcb, float* __restrict__ biasFc){
  int c = blockIdx.x*256 + threadIdx.x;   // 32768 total
  int e = c >> 12, cl = c & 4095;
  int g = cl >> 5, w = cl & 31;
  int j = (w >> 4)*2048 + g*16 + (w & 15);
  biasFc[c] = fcb[e*4096 + j];
}

// ---------------- layernorms ----------------

__global__ __launch_bounds__(256) void ln1_kernel(const float* __restrict__ x, const float* __restrict__ g,
                                                  const float* __restrict__ b, bf16* __restrict__ h){
  const int row = blockIdx.x, tid = threadIdx.x;
  const int lane = tid & 63, wave = tid >> 6;
  const float4 v = reinterpret_cast<const float4*>(x + (size_t)row*1024)[tid];
  float s1 = v.x + v.y + v.z + v.w;
  float s2 = v.x*v.x + v.y*v.y + v.z*v.z + v.w*v.w;
  #pragma unroll
  for (int off=1; off<64; off<<=1){ s1 += __shfl_xor(s1, off); s2 += __shfl_xor(s2, off); }
  __shared__ float rb[8];
  if (lane == 0){ rb[wave] = s1; rb[4+wave] = s2; }
  __syncthreads();
  s1 = rb[0]+rb[1]+rb[2]+rb[3];
  s2 = rb[4]+rb[5]+rb[6]+rb[7];
  const float mu = s1 * (1.f/1024.f);
  const float rst = rsqrtf(s2 * (1.f/1024.f) - mu*mu + 1e-5f);
  const float4 gg = reinterpret_cast<const float4*>(g)[tid];
  const float4 bb = reinterpret_cast<const float4*>(b)[tid];
  ushort4 st;
  st.x = f2bf((v.x-mu)*rst*gg.x + bb.x);
  st.y = f2bf((v.y-mu)*rst*gg.y + bb.y);
  st.z = f2bf((v.z-mu)*rst*gg.z + bb.z);
  st.w = f2bf((v.w-mu)*rst*gg.w + bb.w);
  reinterpret_cast<ushort4*>(h + (size_t)row*1024)[tid] = st;
}

__global__ __launch_bounds__(256) void ln2gate_kernel(const float* __restrict__ xr, const float* __restrict__ g,
    const float* __restrict__ b, const float* __restrict__ gw, const float* __restrict__ gb,
    bf16* __restrict__ h2, float* __restrict__ gate){
  const int row = blockIdx.x, tid = threadIdx.x;
  const int lane = tid & 63, wave = tid >> 6;
  const float4 v = reinterpret_cast<const float4*>(xr + (size_t)row*1024)[tid];
  float s1 = v.x+v.y+v.z+v.w, s2 = v.x*v.x+v.y*v.y+v.z*v.z+v.w*v.w;
  #pragma unroll
  for (int off=1; off<64; off<<=1){ s1 += __shfl_xor(s1, off); s2 += __shfl_xor(s2, off); }
  __shared__ float rb[8];
  if (lane == 0){ rb[wave] = s1; rb[4+wave] = s2; }
  __syncthreads();
  s1 = rb[0]+rb[1]+rb[2]+rb[3];
  s2 = rb[4]+rb[5]+rb[6]+rb[7];
  const float mu = s1*(1.f/1024.f);
  const float rst = rsqrtf(s2*(1.f/1024.f) - mu*mu + 1e-5f);
  const int c = tid*4;
  const float4 gg = reinterpret_cast<const float4*>(g)[tid];
  const float4 bb = reinterpret_cast<const float4*>(b)[tid];
  float nh[4];
  nh[0] = (v.x-mu)*rst*gg.x + bb.x;
  nh[1] = (v.y-mu)*rst*gg.y + bb.y;
  nh[2] = (v.z-mu)*rst*gg.z + bb.z;
  nh[3] = (v.w-mu)*rst*gg.w + bb.w;
  ushort4 st; st.x = f2bf(nh[0]); st.y = f2bf(nh[1]); st.z = f2bf(nh[2]); st.w = f2bf(nh[3]);
  reinterpret_cast<ushort4*>(h2 + (size_t)row*1024)[tid] = st;
  float gp[8];
  #pragma unroll
  for (int e=0;e<8;e++)
    gp[e] = nh[0]*gw[(c+0)*8+e] + nh[1]*gw[(c+1)*8+e] + nh[2]*gw[(c+2)*8+e] + nh[3]*gw[(c+3)*8+e];
  #pragma unroll
  for (int off=1; off<64; off<<=1)
    #pragma unroll
    for (int e=0;e<8;e++) gp[e] += __shfl_xor(gp[e], off);
  __shared__ float gbuf[4][8];
  if (lane == 0)
    #pragma unroll
    for (int e=0;e<8;e++) gbuf[wave][e] = gp[e];
  __syncthreads();
  if (tid == 0){
    float l[8], mx = -1e30f;
    #pragma unroll
    for (int e=0;e<8;e++){ l[e] = gbuf[0][e]+gbuf[1][e]+gbuf[2][e]+gbuf[3][e] + gb[e]; mx = fmaxf(mx, l[e]); }
    float se = 0.f;
    #pragma unroll
    for (int e=0;e<8;e++){ l[e] = __expf(l[e]-mx); se += l[e]; }
    const float inv = 1.f/se;
    #pragma unroll
    for (int e=0;e<8;e++) gate[row*8+e] = l[e]*inv;
  }
}

// ---------------- small GEMM (128x128, m97 structure): QKV / attn-out / MoE-out split-K ----------------
// EPI 0: outb = bf16(acc + bias[c]); EPI 1: outf = acc + bias + resid; EPI 4: split-K fp32 partials.
template<int EPI>
__global__ __launch_bounds__(256) void gemm_bt(
    const bf16* __restrict__ A, const bf16* __restrict__ BT,
    int N, int K, int kPerSlice,
    bf16* __restrict__ outb, float* __restrict__ outf,
    const float* __restrict__ bias, const float* __restrict__ resid,
    const float* __restrict__ gate)
{
  __shared__ __align__(16) bf16 As[128*32];
  __shared__ __align__(16) bf16 Bs[128*32];
  const int tid = threadIdx.x;
  const int lane = tid & 63, wave = tid >> 6;
  const int wr = wave >> 1, wc = wave & 1;
  const int lr = lane & 15, lg = lane >> 4;
  const int row0 = blockIdx.y * 128, col0 = blockIdx.x * 128;
  const int kstart = blockIdx.z * kPerSlice, kend = kstart + kPerSlice;

  const int swzA = lg ^ ((lr >> 1) & 3);

  f32x4 acc[4][4];
  #pragma unroll
  for (int i=0;i<4;i++)
    #pragma unroll
    for (int j=0;j<4;j++) acc[i][j] = (f32x4){0.f,0.f,0.f,0.f};

  for (int k0 = kstart; k0 < kend; k0 += 32){
    if (k0 != kstart) __syncthreads();
    #pragma unroll
    for (int i=0;i<2;i++){
      int ch = i*256 + tid;
      int r = ch >> 2, c = ch & 3;
      int cs = c ^ ((r >> 1) & 3);
      gload_lds16(A  + (size_t)(row0 + r)*K + k0 + cs*8, (void*)&As[ch*8]);
      gload_lds16(BT + (size_t)(col0 + r)*K + k0 + cs*8, (void*)&Bs[ch*8]);
    }
    __syncthreads();
    bf16x8 a[4], bfr[4];
    #pragma unroll
    for (int mi=0;mi<4;mi++) a[mi] = *reinterpret_cast<const bf16x8*>(&As[(wr*64 + mi*16 + lr)*32 + swzA*8]);
    #pragma unroll
    for (int ni=0;ni<4;ni++) bfr[ni] = *reinterpret_cast<const bf16x8*>(&Bs[(wc*64 + ni*16 + lr)*32 + swzA*8]);
    #pragma unroll
    for (int mi=0;mi<4;mi++)
      #pragma unroll
      for (int ni=0;ni<4;ni++)
        acc[mi][ni] = __builtin_amdgcn_mfma_f32_16x16x32_bf16(a[mi], bfr[ni], acc[mi][ni], 0,0,0);
  }

  const int rbase0 = row0 + wr*64;
  #pragma unroll
  for (int mi=0;mi<4;mi++){
    const int r4 = rbase0 + mi*16 + lg*4;
    #pragma unroll
    for (int ni=0;ni<4;ni++){
      const int c = col0 + wc*64 + ni*16 + lr;
      #pragma unroll
      for (int j=0;j<4;j++){
        const int rr = r4 + j;
        float v = acc[mi][ni][j];
        if (EPI == 0) outb[(size_t)rr*N + c] = __float2bfloat16(v + bias[c]);
        else if (EPI == 1) outf[(size_t)rr*N + c] = v + bias[c] + resid[(size_t)rr*N + c];
        else outf[(size_t)blockIdx.z*4194304 + (size_t)rr*1024 + c] = v;   // EPI 4
      }
    }
  }
}

// ---------------- 256x256 8-phase GEMM (T2+T3+T4+T5) for the MoE fc GEMM ----------------
// Stage placement (race-audited; rdA(mh) spans BOTH A-halves per wr, so A-stages may ONLY
// be issued after the ph4 leading BAR which orders all waves' ph3 lgkmcnt(0) drains):
//   ph1: (t+1,B0),(t+1,B1)   [other-parity buffer, last read 2 barriers ago -> safe]
//   ph4 (after BAR): (t+2,A0),(t+2,A1)  [current buffer, all reads certified drained]
// Boundary: VMC(4) retires exactly tile t+1's 4 halves (FIFO), keeps (t+2,A*) in flight.
// LAST iteration: VMC(0) on BOTH tile boundaries (the (t+2,A*) no-ops shift the FIFO window;
// unconditional VMC(2/4) would leave tile t+1's B-halves uncertified -> round-6 latent race).
template<int EPI>
__global__ __launch_bounds__(512, 2) void gemm256(
    const bf16* __restrict__ A, const bf16* __restrict__ BT,
    int K, int kPerSlice,
    bf16* __restrict__ outb, float* __restrict__ outf,
    const float* __restrict__ bias, const float* __restrict__ gate)
{
  __shared__ __align__(16) bf16 lds[2][2][16384];   // [buf][A=0/B=1][256*64]
  const int tid = threadIdx.x;
  const int lane = tid & 63, wave = tid >> 6;
  const int wr = wave >> 2, wc = wave & 3;
  const int lr = lane & 15, lg = lane >> 4;
  const int row0 = blockIdx.y * 256, col0 = blockIdx.x * 256;
  const int kstart = blockIdx.z * kPerSlice;
  const int NT = kPerSlice >> 6;
  const int NITER = NT >> 1;

  f32x4 acc[8][4];
  #pragma unroll
  for (int i=0;i<8;i++)
    #pragma unroll
    for (int j=0;j<4;j++) acc[i][j] = (f32x4){0.f,0.f,0.f,0.f};

  auto stage = [&](int t, int ht){
    if (t >= NT) return;
    const bf16* gbase = (ht < 2) ? (A  + (size_t)(row0 + (ht&1)*128) * K)
                                 : (BT + (size_t)(col0 + (ht&1)*128) * K);
    const int k0 = kstart + t*64;
    bf16* dst = &lds[t&1][ht>>1][(ht&1)*8192];
    #pragma unroll
    for (int l=0;l<2;l++){
      const int c = tid + l*512;
      const int r = c >> 3, col16 = c & 7;
      const int cs = col16 ^ (r & 7);
      gload_lds16(gbase + (size_t)r*K + k0 + cs*8, (void*)&dst[c*8]);
    }
  };

  bf16x8 afr[4][2], bfr[4][2];
  auto rdA = [&](int mh, int buf){
    #pragma unroll
    for (int m2=0;m2<4;m2++)
      #pragma unroll
      for (int kk=0;kk<2;kk++){
        const int row = wr*128 + mh*64 + m2*16 + lr;
        afr[m2][kk] = *reinterpret_cast<const bf16x8*>(
            &lds[buf][0][row*64 + (((kk*4+lg) ^ (lr&7))*8)]);
      }
  };
  auto rdB = [&](int nh, int buf){
    #pragma unroll
    for (int n2=0;n2<2;n2++)
      #pragma unroll
      for (int kk=0;kk<2;kk++){
        const int row = wc*64 + (nh*2+n2)*16 + lr;
        bfr[nh*2+n2][kk] = *reinterpret_cast<const bf16x8*>(
            &lds[buf][1][row*64 + (((kk*4+lg) ^ (lr&7))*8)]);
      }
  };
  auto mfmaQ = [&](int mh, int nh){
    __builtin_amdgcn_s_setprio(1);
    #pragma unroll
    for (int m2=0;m2<4;m2++)
      #pragma unroll
      for (int n2=0;n2<2;n2++)
        #pragma unroll
        for (int kk=0;kk<2;kk++)
          acc[mh*4+m2][nh*2+n2] = __builtin_amdgcn_mfma_f32_16x16x32_bf16(
              afr[m2][kk], bfr[nh*2+n2][kk], acc[mh*4+m2][nh*2+n2], 0,0,0);
    __builtin_amdgcn_s_setprio(0);
  };

#define BAR()   __builtin_amdgcn_s_barrier()
#define LGKM0() do { asm volatile("s_waitcnt lgkmcnt(0)" ::: "memory"); \
                     __builtin_amdgcn_sched_barrier(0); } while(0)
#define VMC(n)  do { asm volatile("s_waitcnt vmcnt(" #n ")" ::: "memory"); \
                     __builtin_amdgcn_sched_barrier(0); } while(0)

  // prologue: tile0's 4 halves + tile1's A-halves; retire tile0, keep 4 loads in flight
  stage(0,0); stage(0,1); stage(0,2); stage(0,3); stage(1,0); stage(1,1);
  VMC(4);
  BAR();

  for (int it = 0; it < NITER; ++it){
    const int tB = it*2;
    const bool more = (it + 1 < NITER);

    // ---- tile tB (buf 0) ----
    stage(tB+1, 2); stage(tB+1, 3); rdA(0,0); rdB(0,0);
    BAR(); LGKM0(); mfmaQ(0,0);
    rdB(1,0);
    BAR(); LGKM0(); mfmaQ(0,1);
    rdA(1,0);
    BAR(); LGKM0(); mfmaQ(1,0);
    BAR(); stage(tB+2, 0); stage(tB+2, 1); mfmaQ(1,1);
    if (more) { VMC(4); } else { VMC(0); }
    BAR();

    // ---- tile tB+1 (buf 1) ----
    stage(tB+2, 2); stage(tB+2, 3); rdA(0,1); rdB(0,1);
    BAR(); LGKM0(); mfmaQ(0,0);
    rdB(1,1);
    BAR(); LGKM0(); mfmaQ(0,1);
    rdA(1,1);
    BAR(); LGKM0(); mfmaQ(1,0);
    BAR(); stage(tB+3, 0); stage(tB+3, 1); mfmaQ(1,1);
    if (more) { VMC(4); } else { VMC(0); }
    BAR();
  }
#undef BAR
#undef LGKM0
#undef VMC

  #pragma unroll
  for (int mi=0;mi<8;mi++){
    const int r4 = row0 + wr*128 + mi*16 + lg*4;
    if (EPI == 2){
      #pragma unroll
      for (int p=0;p<2;p++){
        const int c1 = col0 + wc*64 + p*32 + lr;      // x1 col; x2 col = c1+16
        const int fg = (c1 >> 5)*16 + lr;             // f_global in [0,16384)
        const int e  = fg >> 11;
        const float b1 = bias[c1], b2 = bias[c1 + 16];
        #pragma unroll
        for (int j=0;j<4;j++){
          const int rr = r4 + j;
          const float x1v = acc[mi][2*p][j] + b1;
          const float x2v = acc[mi][2*p+1][j] + b2;
          const float gl = fast_gelu(x2v);
          outb[(size_t)rr*16384 + fg] = __float2bfloat16(x1v * gl * gate[rr*8 + e]);
        }
      }
    } else {  // EPI 4 (unused this round)
      #pragma unroll
      for (int ni=0;ni<4;ni++){
        const int c = col0 + wc*64 + ni*16 + lr;
        #pragma unroll
        for (int j=0;j<4;j++)
          outf[(size_t)blockIdx.z*4194304 + (size_t)(r4 + j)*1024 + c] = acc[mi][ni][j];
      }
    }
  }
}

// ---------------- RoPE (in-place on qkv; folds 1/sqrt(64) into q) ----------------
__global__ __launch_bounds__(256) void rope_kernel(bf16* __restrict__ qkv, const int* __restrict__ posoff){
  const int idx = blockIdx.x*256 + threadIdx.x;   // 2*2048*16*32 = 2,097,152
  const int i = idx & 31;
  const int h = (idx >> 5) & 15;
  const int n = idx >> 9;
  const float pos = (float)((n & 2047) + posoff[0]);
  const float ang = pos * __expf(-0.2878231366f * (float)i);   // ln(10000)/32
  float sn, cs;
  __sincosf(ang, &sn, &cs);
  size_t base = (size_t)n*3072 + h*64 + i;
  {
    float x1 = __bfloat162float(qkv[base]);
    float x2 = __bfloat162float(qkv[base + 32]);
    qkv[base]      = __float2bfloat16((x1*cs - x2*sn) * 0.125f);
    qkv[base + 32] = __float2bfloat16((x1*sn + x2*cs) * 0.125f);
  }
  {
    float x1 = __bfloat162float(qkv[base + 1024]);
    float x2 = __bfloat162float(qkv[base + 1056]);
    qkv[base + 1024] = __float2bfloat16(x1*cs - x2*sn);
    qkv[base + 1056] = __float2bfloat16(x1*sn + x2*cs);
  }
}

// ---------------- flash attention (causal), 64-q x 64-k tiles, 4 waves ----------------
// Balanced pairing: block x=i handles qt=i then qt=31-i (33 k-tiles each, no tail).
// T14 async-stage: K/V for tile kt+1 loaded to regs during tile kt's compute.
__global__ __launch_bounds__(256) void attn_kernel(const bf16* __restrict__ qkv, bf16* __restrict__ o){
  const int bh = blockIdx.y;
  const int b = bh >> 4, h = bh & 15;
  const int tid = threadIdx.x, lane = tid & 63, wave = tid >> 6;
  const int lr = lane & 15, lg = lane >> 4;
  __shared__ __align__(16) bf16 Kt[64*72];      // K tile row-major, padded stride 72
  __shared__ __align__(16) bf16 Vt[64*72];      // V^T tile: Vt[d][kj]
  __shared__ __align__(16) bf16 P[4][16*72];    // per-wave P, padded

  const size_t bbase = (size_t)b*2048*3072;

  bf16x8 kreg[2];
  bf16 vreg[16];

  auto loadKV = [&](int kt){
    #pragma unroll
    for (int i=0;i<2;i++){
      int ch = i*256 + tid;
      int r = ch >> 3, c = ch & 7;
      kreg[i] = *reinterpret_cast<const bf16x8*>(&qkv[bbase + (size_t)(kt*64+r)*3072 + 1024 + h*64 + c*8]);
    }
    #pragma unroll
    for (int i=0;i<16;i++){
      int idx = i*256 + tid;
      int r = idx >> 6, d = idx & 63;
      vreg[i] = qkv[bbase + (size_t)(kt*64+r)*3072 + 2048 + h*64 + d];
    }
  };
  auto writeKV = [&](){
    #pragma unroll
    for (int i=0;i<2;i++){
      int ch = i*256 + tid;
      int r = ch >> 3, c = ch & 7;
      *reinterpret_cast<bf16x8*>(&Kt[r*72 + c*8]) = kreg[i];
    }
    #pragma unroll
    for (int i=0;i<16;i++){
      int idx = i*256 + tid;
      int r = idx >> 6, d = idx & 63;
      Vt[d*72 + r] = vreg[i];
    }
  };

  #pragma unroll 1
  for (int half=0; half<2; half++){
    const int qt = (half == 0) ? (int)blockIdx.x : 31 - (int)blockIdx.x;
    const int qrow = qt*64 + wave*16 + lr;
    bf16x8 qf[2];
    #pragma unroll
    for (int kk=0;kk<2;kk++)
      qf[kk] = *reinterpret_cast<const bf16x8*>(&qkv[bbase + (size_t)qrow*3072 + h*64 + kk*32 + lg*8]);

    f32x4 oacc[4];
    #pragma unroll
    for (int ni=0;ni<4;ni++) oacc[ni] = (f32x4){0.f,0.f,0.f,0.f};
    float mrow[4] = {-1e30f,-1e30f,-1e30f,-1e30f};
    float srow[4] = {0.f,0.f,0.f,0.f};

    loadKV(0);

    #pragma unroll 1
    for (int kt=0; kt<=qt; kt++){
      __syncthreads();
      writeKV();
      __syncthreads();
      if (kt < qt) loadKV(kt+1);      // T14: in flight during compute below

      f32x4 sacc[4];
      #pragma unroll
      for (int ni=0;ni<4;ni++) sacc[ni] = (f32x4){0.f,0.f,0.f,0.f};
      __builtin_amdgcn_s_setprio(1);
      #pragma unroll
      for (int kk=0;kk<2;kk++)
        #pragma unroll
        for (int ni=0;ni<4;ni++){
          bf16x8 kb = *reinterpret_cast<const bf16x8*>(&Kt[(ni*16+lr)*72 + kk*32 + lg*8]);
          sacc[ni] = __builtin_amdgcn_mfma_f32_16x16x32_bf16(qf[kk], kb, sacc[ni], 0,0,0);
        }
      __builtin_amdgcn_s_setprio(0);
      if (kt == qt){
        #pragma unroll
        for (int ni=0;ni<4;ni++)
          #pragma unroll
          for (int j=0;j<4;j++)
            if (ni*16 + lr > wave*16 + lg*4 + j) sacc[ni][j] = -1e30f;
      }
      float pm[4];
      #pragma unroll
      for (int j=0;j<4;j++)
        pm[j] = fmaxf(fmaxf(sacc[0][j], sacc[1][j]), fmaxf(sacc[2][j], sacc[3][j]));
      #pragma unroll
      for (int off=1; off<16; off<<=1)
        #pragma unroll
        for (int j=0;j<4;j++) pm[j] = fmaxf(pm[j], __shfl_xor(pm[j], off));
      float sc[4], rs[4];
      #pragma unroll
      for (int j=0;j<4;j++){
        float mn = fmaxf(mrow[j], pm[j]);
        sc[j] = __expf(mrow[j] - mn);
        mrow[j] = mn;
        rs[j] = 0.f;
      }
      #pragma unroll
      for (int ni=0;ni<4;ni++)
        #pragma unroll
        for (int j=0;j<4;j++){
          float p = __expf(sacc[ni][j] - mrow[j]);
          sacc[ni][j] = p;
          rs[j] += p;
        }
      #pragma unroll
      for (int off=1; off<16; off<<=1)
        #pragma unroll
        for (int j=0;j<4;j++) rs[j] += __shfl_xor(rs[j], off);
      #pragma unroll
      for (int j=0;j<4;j++) srow[j] = srow[j]*sc[j] + rs[j];
      #pragma unroll
      for (int ni=0;ni<4;ni++)
        #pragma unroll
        for (int j=0;j<4;j++)
          P[wave][(lg*4+j)*72 + ni*16 + lr] = __float2bfloat16(sacc[ni][j]);
      #pragma unroll
      for (int ni=0;ni<4;ni++)
        #pragma unroll
        for (int j=0;j<4;j++) oacc[ni][j] *= sc[j];
      asm volatile("s_waitcnt lgkmcnt(0)" ::: "memory");
      __builtin_amdgcn_sched_barrier(0);
      bf16x8 pa0 = *reinterpret_cast<const bf16x8*>(&P[wave][lr*72 + lg*8]);
      bf16x8 pa1 = *reinterpret_cast<const bf16x8*>(&P[wave][lr*72 + 32 + lg*8]);
      __builtin_amdgcn_s_setprio(1);
      #pragma unroll
      for (int ni=0;ni<4;ni++){
        bf16x8 vb0 = *reinterpret_cast<const bf16x8*>(&Vt[(ni*16+lr)*72 + lg*8]);
        oacc[ni] = __builtin_amdgcn_mfma_f32_16x16x32_bf16(pa0, vb0, oacc[ni], 0,0,0);
        bf16x8 vb1 = *reinterpret_cast<const bf16x8*>(&Vt[(ni*16+lr)*72 + 32 + lg*8]);
        oacc[ni] = __builtin_amdgcn_mfma_f32_16x16x32_bf16(pa1, vb1, oacc[ni], 0,0,0);
      }
      __builtin_amdgcn_s_setprio(0);
    }
    #pragma unroll
    for (int ni=0;ni<4;ni++)
      #pragma unroll
      for (int j=0;j<4;j++){
        int row = qt*64 + wave*16 + lg*4 + j;
        int col = h*64 + ni*16 + lr;
        o[(size_t)(b*2048 + row)*1024 + col] = __float2bfloat16(oacc[ni][j] / srow[j]);
      }
  }
}

// ---------------- final reduce: out = x_res + sum_s partial + sum_e gate*eout_b ----------------
__global__ __launch_bounds__(256) void reduce_out_kernel(const float* __restrict__ partial, const float* __restrict__ xres,
    const float* __restrict__ gate, const float* __restrict__ eob, float* __restrict__ out){
  const int idx = blockIdx.x*256 + threadIdx.x;   // float4 index, 1,048,576 total
  float4 v = reinterpret_cast<const float4*>(xres)[idx];
  #pragma unroll
  for (int s=0;s<4;s++){
    float4 p = reinterpret_cast<const float4*>(partial + (size_t)s*4194304)[idx];
    v.x += p.x; v.y += p.y; v.z += p.z; v.w += p.w;
  }
  const int n = idx >> 8;
  const int c = (idx << 2) & 1023;
  #pragma unroll
  for (int e=0;e<8;e++){
    const float gp = gate[n*8+e];
    const float4 eb = *reinterpret_cast<const float4*>(&eob[e*1024 + c]);
    v.x += gp*eb.x; v.y += gp*eb.y; v.z += gp*eb.z; v.w += gp*eb.w;
  }
  reinterpret_cast<float4*>(out)[idx] = v;
}

__global__ __launch_bounds__(256) void util_kernel(const float* __restrict__ gate, float* __restrict__ outloss){
  const int tid = threadIdx.x, lane = tid & 63, wave = tid >> 6;
  float p[8] = {0,0,0,0,0,0,0,0};
  for (int r = tid; r < 4096; r += 256)
    #pragma unroll
    for (int e=0;e<8;e++) p[e] += gate[r*8+e];
  #pragma unroll
  for (int off=1; off<64; off<<=1)
    #pragma unroll
    for (int e=0;e<8;e++) p[e] += __shfl_xor(p[e], off);
  __shared__ float rb[4][8];
  if (lane == 0)
    #pragma unroll
    for (int e=0;e<8;e++) rb[wave][e] = p[e];
  __syncthreads();
  if (tid == 0){
    float loss = 0.f;
    #pragma unroll
    for (int e=0;e<8;e++){
      float u = (rb[0][e]+rb[1][e]+rb[2][e]+rb[3][e]) * (1.f/4096.f) - 0.125f;
      loss += u*u;
    }
    outloss[0] = loss;
  }
}

extern "C" void kernel_launch(void* const* d_in, const int* in_sizes, int n_in,
                              void* d_out, int out_size, void* d_ws, size_t ws_size,
                              hipStream_t stream){
  const float* x    = (const float*)d_in[0];
  const int*   poff = (const int*)  d_in[2];
  const float* ln1g = (const float*)d_in[3];
  const float* ln1b = (const float*)d_in[4];
  const float* qkvw = (const float*)d_in[5];
  const float* qkvb = (const float*)d_in[6];
  const float* aow  = (const float*)d_in[7];
  const float* aob  = (const float*)d_in[8];
  const float* ln2g = (const float*)d_in[9];
  const float* ln2b = (const float*)d_in[10];
  const float* gw   = (const float*)d_in[11];
  const float* gb   = (const float*)d_in[12];
  const float* fcw  = (const float*)d_in[13];
  const float* fcb  = (const float*)d_in[14];
  const float* eow  = (const float*)d_in[15];
  const float* eob  = (const float*)d_in[16];
  float* out = (float*)d_out;
  char* ws = (char*)d_ws;

  if (ws_size < 260308992ull) return;  // layout below needs ~248 MB

  bf16*  WqkvT  = (bf16*)(ws + 0);          //  6.3 MB
  bf16*  WattnT = (bf16*)(ws + 6291456);    //  2.1 MB
  bf16*  h1     = (bf16*)(ws + 8388608);    //  8.4 MB
  bf16*  qkv    = (bf16*)(ws + 16777216);   // 25.2 MB
  bf16*  o      = (bf16*)(ws + 41943040);   //  8.4 MB
  bf16*  act    = (bf16*)(ws + 0);          // 134 MB (overwrites the 5 above)
  bf16*  WfcT   = (bf16*)(ws + 134217728);  // 67 MB
  float* partial= (float*)(ws + 134217728); // 64 MB (overwrites WfcT after fc GEMM)
  bf16*  WeoutT = (bf16*)(ws + 201326592);  // 33.6 MB
  float* biasFc = (float*)(ws + 234881024);
  float* xres   = (float*)(ws + 235012096); // 16.8 MB
  bf16*  h2     = (bf16*)(ws + 251789312);  //  8.4 MB
  float* gate   = (float*)(ws + 260177920);

  packT_kernel<<<dim3(96,32), 256, 0, stream>>>(qkvw, WqkvT, 1024, 3072);
  packT_kernel<<<dim3(32,32), 256, 0, stream>>>(aow, WattnT, 1024, 1024);
  pack_fc_kernel<<<dim3(128,32,8), 256, 0, stream>>>(fcw, WfcT);
  pack_eout_kernel<<<dim3(64,32,8), 256, 0, stream>>>(eow, WeoutT);
  pack_biasfc_kernel<<<128, 256, 0, stream>>>(fcb, biasFc);

  ln1_kernel<<<4096, 256, 0, stream>>>(x, ln1g, ln1b, h1);
  gemm_bt<0><<<dim3(24,32), 256, 0, stream>>>(h1, WqkvT, 3072, 1024, 1024, qkv, nullptr, qkvb, nullptr, nullptr);
  rope_kernel<<<8192, 256, 0, stream>>>(qkv, poff);
  attn_kernel<<<dim3(16,32), 256, 0, stream>>>(qkv, o);
  gemm_bt<1><<<dim3(8,32), 256, 0, stream>>>(o, WattnT, 1024, 1024, 1024, nullptr, xres, aob, x, nullptr);
  ln2gate_kernel<<<4096, 256, 0, stream>>>(xres, ln2g, ln2b, gw, gb, h2, gate);
  gemm256<2><<<dim3(128,16), 512, 0, stream>>>(h2, WfcT, 1024, 1024, act, nullptr, biasFc, gate);
  gemm_bt<4><<<dim3(8,32,4), 256, 0, stream>>>(act, WeoutT, 1024, 16384, 4096, nullptr, partial, nullptr, nullptr, nullptr);
  reduce_out_kernel<<<4096, 256, 0, stream>>>(partial, xres, gate, eob, out);
  util_kernel<<<1, 256, 0, stream>>>(gate, out + 4194304);
}

// Round 9
// 694.795 us; speedup vs baseline: 1.1896x; 1.1896x over previous
//
#include <hip/hip_runtime.h>
#include <hip/hip_bf16.h>

typedef __hip_bfloat16 bf16;
typedef short bf16x8 __attribute__((ext_vector_type(8)));
typedef float f32x4 __attribute__((ext_vector_type(4)));

__device__ __forceinline__ unsigned short f2bf(float f){
  __hip_bfloat16 h = __float2bfloat16(f);
  unsigned short u; __builtin_memcpy(&u, &h, 2); return u;
}

__device__ __forceinline__ void gload_lds16(const void* g, void* l){
  __builtin_amdgcn_global_load_lds((const __attribute__((address_space(1))) unsigned int*)g,
                                   (__attribute__((address_space(3))) unsigned int*)l, 16, 0, 0);
}

// fast GELU: x*sigmoid(1.59577(x+0.044715x^3)) == tanh-approx GELU; |err| ~1e-3 << bf16 ulp of act
__device__ __forceinline__ float fast_gelu(float x){
  float t = 1.5957691216f * x * (1.f + 0.044715f * x * x);
  return x / (1.f + __expf(-t));
}

// ---------------- weight packing (fp32 -> bf16, transposed to B^T layout) ----------------

__global__ __launch_bounds__(256) void packT_kernel(const float* __restrict__ in, bf16* __restrict__ out, int R, int C){
  __shared__ float tile[32][33];
  const int tid = threadIdx.x;
  const int tc = tid & 31, tr = tid >> 5;
  const int r0 = blockIdx.y * 32, c0 = blockIdx.x * 32;
  #pragma unroll
  for (int i=0;i<4;i++)
    tile[tr + i*8][tc] = in[(size_t)(r0 + tr + i*8)*C + c0 + tc];
  __syncthreads();
  #pragma unroll
  for (int i=0;i<4;i++){
    int oc = tr + i*8;
    out[(size_t)(c0 + oc)*R + r0 + tc] = __float2bfloat16(tile[tc][oc]);
  }
}

// fc_w (8,1024,4096) -> WfcT (32768,1024); row c = e*4096 + cl(j),
// cl(j) = ((j&2047)>>4)*32 + (j>>11)*16 + (j&15)
__global__ __launch_bounds__(256) void pack_fc_kernel(const float* __restrict__ fcw, bf16* __restrict__ out){
  __shared__ float tile[32][33];
  const int tid = threadIdx.x;
  const int tc = tid & 31, tr = tid >> 5;
  const int e = blockIdx.z;
  const int d0 = blockIdx.y * 32, j0 = blockIdx.x * 32;
  #pragma unroll
  for (int i=0;i<4;i++)
    tile[tr + i*8][tc] = fcw[((size_t)e*1024 + d0 + tr + i*8)*4096 + j0 + tc];
  __syncthreads();
  #pragma unroll
  for (int i=0;i<4;i++){
    int j = j0 + tr + i*8;
    int cl = ((j & 2047) >> 4)*32 + (j >> 11)*16 + (j & 15);
    out[((size_t)e*4096 + cl)*1024 + d0 + tc] = __float2bfloat16(tile[tc][tr + i*8]);
  }
}

// eout_w (8,2048,1024) -> WeoutT (1024,16384): out[d][e*2048+f] = in[e][f][d]
__global__ __launch_bounds__(256) void pack_eout_kernel(const float* __restrict__ eow, bf16* __restrict__ out){
  __shared__ float tile[32][33];
  const int tid = threadIdx.x;
  const int tc = tid & 31, tr = tid >> 5;
  const int e = blockIdx.z;
  const int d0 = blockIdx.y * 32, f0 = blockIdx.x * 32;
  #pragma unroll
  for (int i=0;i<4;i++)
    tile[tr + i*8][tc] = eow[((size_t)e*2048 + f0 + tr + i*8)*1024 + d0 + tc];
  __syncthreads();
  #pragma unroll
  for (int i=0;i<4;i++){
    int d = d0 + tr + i*8;
    out[(size_t)d*16384 + e*2048 + f0 + tc] = __float2bfloat16(tile[tc][tr + i*8]);
  }
}

__global__ __launch_bounds__(256) void pack_biasfc_kernel(const float* __restrict__ fcb, float* __restrict__ biasFc){
  int c = blockIdx.x*256 + threadIdx.x;   // 32768 total
  int e = c >> 12, cl = c & 4095;
  int g = cl >> 5, w = cl & 31;
  int j = (w >> 4)*2048 + g*16 + (w & 15);
  biasFc[c] = fcb[e*4096 + j];
}

// ---------------- layernorms ----------------

__global__ __launch_bounds__(256) void ln1_kernel(const float* __restrict__ x, const float* __restrict__ g,
                                                  const float* __restrict__ b, bf16* __restrict__ h){
  const int row = blockIdx.x, tid = threadIdx.x;
  const int lane = tid & 63, wave = tid >> 6;
  const float4 v = reinterpret_cast<const float4*>(x + (size_t)row*1024)[tid];
  float s1 = v.x + v.y + v.z + v.w;
  float s2 = v.x*v.x + v.y*v.y + v.z*v.z + v.w*v.w;
  #pragma unroll
  for (int off=1; off<64; off<<=1){ s1 += __shfl_xor(s1, off); s2 += __shfl_xor(s2, off); }
  __shared__ float rb[8];
  if (lane == 0){ rb[wave] = s1; rb[4+wave] = s2; }
  __syncthreads();
  s1 = rb[0]+rb[1]+rb[2]+rb[3];
  s2 = rb[4]+rb[5]+rb[6]+rb[7];
  const float mu = s1 * (1.f/1024.f);
  const float rst = rsqrtf(s2 * (1.f/1024.f) - mu*mu + 1e-5f);
  const float4 gg = reinterpret_cast<const float4*>(g)[tid];
  const float4 bb = reinterpret_cast<const float4*>(b)[tid];
  ushort4 st;
  st.x = f2bf((v.x-mu)*rst*gg.x + bb.x);
  st.y = f2bf((v.y-mu)*rst*gg.y + bb.y);
  st.z = f2bf((v.z-mu)*rst*gg.z + bb.z);
  st.w = f2bf((v.w-mu)*rst*gg.w + bb.w);
  reinterpret_cast<ushort4*>(h + (size_t)row*1024)[tid] = st;
}

__global__ __launch_bounds__(256) void ln2gate_kernel(const float* __restrict__ xr, const float* __restrict__ g,
    const float* __restrict__ b, const float* __restrict__ gw, const float* __restrict__ gb,
    bf16* __restrict__ h2, float* __restrict__ gate){
  const int row = blockIdx.x, tid = threadIdx.x;
  const int lane = tid & 63, wave = tid >> 6;
  const float4 v = reinterpret_cast<const float4*>(xr + (size_t)row*1024)[tid];
  float s1 = v.x+v.y+v.z+v.w, s2 = v.x*v.x+v.y*v.y+v.z*v.z+v.w*v.w;
  #pragma unroll
  for (int off=1; off<64; off<<=1){ s1 += __shfl_xor(s1, off); s2 += __shfl_xor(s2, off); }
  __shared__ float rb[8];
  if (lane == 0){ rb[wave] = s1; rb[4+wave] = s2; }
  __syncthreads();
  s1 = rb[0]+rb[1]+rb[2]+rb[3];
  s2 = rb[4]+rb[5]+rb[6]+rb[7];
  const float mu = s1*(1.f/1024.f);
  const float rst = rsqrtf(s2*(1.f/1024.f) - mu*mu + 1e-5f);
  const int c = tid*4;
  const float4 gg = reinterpret_cast<const float4*>(g)[tid];
  const float4 bb = reinterpret_cast<const float4*>(b)[tid];
  float nh[4];
  nh[0] = (v.x-mu)*rst*gg.x + bb.x;
  nh[1] = (v.y-mu)*rst*gg.y + bb.y;
  nh[2] = (v.z-mu)*rst*gg.z + bb.z;
  nh[3] = (v.w-mu)*rst*gg.w + bb.w;
  ushort4 st; st.x = f2bf(nh[0]); st.y = f2bf(nh[1]); st.z = f2bf(nh[2]); st.w = f2bf(nh[3]);
  reinterpret_cast<ushort4*>(h2 + (size_t)row*1024)[tid] = st;
  float gp[8];
  #pragma unroll
  for (int e=0;e<8;e++)
    gp[e] = nh[0]*gw[(c+0)*8+e] + nh[1]*gw[(c+1)*8+e] + nh[2]*gw[(c+2)*8+e] + nh[3]*gw[(c+3)*8+e];
  #pragma unroll
  for (int off=1; off<64; off<<=1)
    #pragma unroll
    for (int e=0;e<8;e++) gp[e] += __shfl_xor(gp[e], off);
  __shared__ float gbuf[4][8];
  if (lane == 0)
    #pragma unroll
    for (int e=0;e<8;e++) gbuf[wave][e] = gp[e];
  __syncthreads();
  if (tid == 0){
    float l[8], mx = -1e30f;
    #pragma unroll
    for (int e=0;e<8;e++){ l[e] = gbuf[0][e]+gbuf[1][e]+gbuf[2][e]+gbuf[3][e] + gb[e]; mx = fmaxf(mx, l[e]); }
    float se = 0.f;
    #pragma unroll
    for (int e=0;e<8;e++){ l[e] = __expf(l[e]-mx); se += l[e]; }
    const float inv = 1.f/se;
    #pragma unroll
    for (int e=0;e<8;e++) gate[row*8+e] = l[e]*inv;
  }
}

// ---------------- small GEMM (128x128, m97 structure) for QKV / attn-out ----------------
template<int EPI>
__global__ __launch_bounds__(256) void gemm_bt(
    const bf16* __restrict__ A, const bf16* __restrict__ BT,
    int N, int K, int kPerSlice,
    bf16* __restrict__ outb, float* __restrict__ outf,
    const float* __restrict__ bias, const float* __restrict__ resid,
    const float* __restrict__ gate)
{
  __shared__ __align__(16) bf16 As[128*32];
  __shared__ __align__(16) bf16 Bs[128*32];
  const int tid = threadIdx.x;
  const int lane = tid & 63, wave = tid >> 6;
  const int wr = wave >> 1, wc = wave & 1;
  const int lr = lane & 15, lg = lane >> 4;
  const int row0 = blockIdx.y * 128, col0 = blockIdx.x * 128;
  const int kstart = blockIdx.z * kPerSlice, kend = kstart + kPerSlice;

  const int swzA = lg ^ ((lr >> 1) & 3);

  f32x4 acc[4][4];
  #pragma unroll
  for (int i=0;i<4;i++)
    #pragma unroll
    for (int j=0;j<4;j++) acc[i][j] = (f32x4){0.f,0.f,0.f,0.f};

  for (int k0 = kstart; k0 < kend; k0 += 32){
    if (k0 != kstart) __syncthreads();
    #pragma unroll
    for (int i=0;i<2;i++){
      int ch = i*256 + tid;
      int r = ch >> 2, c = ch & 3;
      int cs = c ^ ((r >> 1) & 3);
      gload_lds16(A  + (size_t)(row0 + r)*K + k0 + cs*8, (void*)&As[ch*8]);
      gload_lds16(BT + (size_t)(col0 + r)*K + k0 + cs*8, (void*)&Bs[ch*8]);
    }
    __syncthreads();
    bf16x8 a[4], bfr[4];
    #pragma unroll
    for (int mi=0;mi<4;mi++) a[mi] = *reinterpret_cast<const bf16x8*>(&As[(wr*64 + mi*16 + lr)*32 + swzA*8]);
    #pragma unroll
    for (int ni=0;ni<4;ni++) bfr[ni] = *reinterpret_cast<const bf16x8*>(&Bs[(wc*64 + ni*16 + lr)*32 + swzA*8]);
    #pragma unroll
    for (int mi=0;mi<4;mi++)
      #pragma unroll
      for (int ni=0;ni<4;ni++)
        acc[mi][ni] = __builtin_amdgcn_mfma_f32_16x16x32_bf16(a[mi], bfr[ni], acc[mi][ni], 0,0,0);
  }

  const int rbase0 = row0 + wr*64;
  #pragma unroll
  for (int mi=0;mi<4;mi++){
    const int r4 = rbase0 + mi*16 + lg*4;
    #pragma unroll
    for (int ni=0;ni<4;ni++){
      const int c = col0 + wc*64 + ni*16 + lr;
      #pragma unroll
      for (int j=0;j<4;j++){
        const int rr = r4 + j;
        float v = acc[mi][ni][j];
        if (EPI == 0) outb[(size_t)rr*N + c] = __float2bfloat16(v + bias[c]);
        else outf[(size_t)rr*N + c] = v + bias[c] + resid[(size_t)rr*N + c];
      }
    }
  }
}

// ---------------- 256x256 8-phase GEMM (T2+T3+T4+T5) for the MoE GEMMs ----------------
// Race-audited stage placement (round 8) + minimal barriers (round 9):
//   In-tile barriers at ph1/ph2/ph3 removed — they ordered nothing: all in-tile reads target
//   buffers certified at the tile boundary; per-wave LGKM0s still order each wave's own reads.
//   Cross-wave hazards and their guards:
//     (a) ph4's (t+2,A*) stage writes the CURRENT A-buffer -> kept ph4 BAR; every wave's A-reads
//         are lgkm-drained before it in program order.
//     (b) tile boundary -> kept VMC+BAR; VMC(4) retires exactly tile t+1's 4 halves (FIFO:
//         each stage = 2 loads/thread; outstanding at boundary = 12 -> retire 8, keep (t+2,A*)).
//   LAST iteration: VMC(0) on BOTH boundaries (stage no-ops shift the FIFO window).
// Waves drift within a tile -> one wave's ds_read service overlaps another's MFMA.
template<int EPI>
__global__ __launch_bounds__(512, 2) void gemm256(
    const bf16* __restrict__ A, const bf16* __restrict__ BT,
    int K, int kPerSlice,
    bf16* __restrict__ outb, float* __restrict__ outf,
    const float* __restrict__ bias, const float* __restrict__ gate)
{
  __shared__ __align__(16) bf16 lds[2][2][16384];   // [buf][A=0/B=1][256*64]
  const int tid = threadIdx.x;
  const int lane = tid & 63, wave = tid >> 6;
  const int wr = wave >> 2, wc = wave & 3;
  const int lr = lane & 15, lg = lane >> 4;
  const int row0 = blockIdx.y * 256, col0 = blockIdx.x * 256;
  const int kstart = blockIdx.z * kPerSlice;
  const int NT = kPerSlice >> 6;
  const int NITER = NT >> 1;

  f32x4 acc[8][4];
  #pragma unroll
  for (int i=0;i<8;i++)
    #pragma unroll
    for (int j=0;j<4;j++) acc[i][j] = (f32x4){0.f,0.f,0.f,0.f};

  auto stage = [&](int t, int ht){
    if (t >= NT) return;
    const bf16* gbase = (ht < 2) ? (A  + (size_t)(row0 + (ht&1)*128) * K)
                                 : (BT + (size_t)(col0 + (ht&1)*128) * K);
    const int k0 = kstart + t*64;
    bf16* dst = &lds[t&1][ht>>1][(ht&1)*8192];
    #pragma unroll
    for (int l=0;l<2;l++){
      const int c = tid + l*512;
      const int r = c >> 3, col16 = c & 7;
      const int cs = col16 ^ (r & 7);
      gload_lds16(gbase + (size_t)r*K + k0 + cs*8, (void*)&dst[c*8]);
    }
  };

  bf16x8 afr[4][2], bfr[4][2];
  auto rdA = [&](int mh, int buf){
    #pragma unroll
    for (int m2=0;m2<4;m2++)
      #pragma unroll
      for (int kk=0;kk<2;kk++){
        const int row = wr*128 + mh*64 + m2*16 + lr;
        afr[m2][kk] = *reinterpret_cast<const bf16x8*>(
            &lds[buf][0][row*64 + (((kk*4+lg) ^ (lr&7))*8)]);
      }
  };
  auto rdB = [&](int nh, int buf){
    #pragma unroll
    for (int n2=0;n2<2;n2++)
      #pragma unroll
      for (int kk=0;kk<2;kk++){
        const int row = wc*64 + (nh*2+n2)*16 + lr;
        bfr[nh*2+n2][kk] = *reinterpret_cast<const bf16x8*>(
            &lds[buf][1][row*64 + (((kk*4+lg) ^ (lr&7))*8)]);
      }
  };
  auto mfmaQ = [&](int mh, int nh){
    __builtin_amdgcn_s_setprio(1);
    #pragma unroll
    for (int m2=0;m2<4;m2++)
      #pragma unroll
      for (int n2=0;n2<2;n2++)
        #pragma unroll
        for (int kk=0;kk<2;kk++)
          acc[mh*4+m2][nh*2+n2] = __builtin_amdgcn_mfma_f32_16x16x32_bf16(
              afr[m2][kk], bfr[nh*2+n2][kk], acc[mh*4+m2][nh*2+n2], 0,0,0);
    __builtin_amdgcn_s_setprio(0);
  };

#define BAR()   __builtin_amdgcn_s_barrier()
#define LGKM0() do { asm volatile("s_waitcnt lgkmcnt(0)" ::: "memory"); \
                     __builtin_amdgcn_sched_barrier(0); } while(0)
#define VMC(n)  do { asm volatile("s_waitcnt vmcnt(" #n ")" ::: "memory"); \
                     __builtin_amdgcn_sched_barrier(0); } while(0)

  // prologue: tile0's 4 halves + tile1's A-halves; retire tile0, keep 4 loads in flight
  stage(0,0); stage(0,1); stage(0,2); stage(0,3); stage(1,0); stage(1,1);
  VMC(4);
  BAR();

  for (int it = 0; it < NITER; ++it){
    const int tB = it*2;
    const bool more = (it + 1 < NITER);

    // ---- tile tB (buf 0) ----
    stage(tB+1, 2); stage(tB+1, 3); rdA(0,0); rdB(0,0);
    LGKM0(); mfmaQ(0,0);
    rdB(1,0);
    LGKM0(); mfmaQ(0,1);
    rdA(1,0);
    LGKM0(); mfmaQ(1,0);
    BAR(); stage(tB+2, 0); stage(tB+2, 1); mfmaQ(1,1);
    if (more) { VMC(4); } else { VMC(0); }
    BAR();

    // ---- tile tB+1 (buf 1) ----
    stage(tB+2, 2); stage(tB+2, 3); rdA(0,1); rdB(0,1);
    LGKM0(); mfmaQ(0,0);
    rdB(1,1);
    LGKM0(); mfmaQ(0,1);
    rdA(1,1);
    LGKM0(); mfmaQ(1,0);
    BAR(); stage(tB+3, 0); stage(tB+3, 1); mfmaQ(1,1);
    if (more) { VMC(4); } else { VMC(0); }
    BAR();
  }
#undef BAR
#undef LGKM0
#undef VMC

  #pragma unroll
  for (int mi=0;mi<8;mi++){
    const int r4 = row0 + wr*128 + mi*16 + lg*4;
    if (EPI == 2){
      #pragma unroll
      for (int p=0;p<2;p++){
        const int c1 = col0 + wc*64 + p*32 + lr;      // x1 col; x2 col = c1+16
        const int fg = (c1 >> 5)*16 + lr;             // f_global in [0,16384)
        const int e  = fg >> 11;
        const float b1 = bias[c1], b2 = bias[c1 + 16];
        #pragma unroll
        for (int j=0;j<4;j++){
          const int rr = r4 + j;
          const float x1v = acc[mi][2*p][j] + b1;
          const float x2v = acc[mi][2*p+1][j] + b2;
          const float gl = fast_gelu(x2v);
          outb[(size_t)rr*16384 + fg] = __float2bfloat16(x1v * gl * gate[rr*8 + e]);
        }
      }
    } else {  // EPI 4: split-K fp32 partials
      #pragma unroll
      for (int ni=0;ni<4;ni++){
        const int c = col0 + wc*64 + ni*16 + lr;
        #pragma unroll
        for (int j=0;j<4;j++)
          outf[(size_t)blockIdx.z*4194304 + (size_t)(r4 + j)*1024 + c] = acc[mi][ni][j];
      }
    }
  }
}

// ---------------- RoPE (in-place on qkv; folds 1/sqrt(64) into q) ----------------
__global__ __launch_bounds__(256) void rope_kernel(bf16* __restrict__ qkv, const int* __restrict__ posoff){
  const int idx = blockIdx.x*256 + threadIdx.x;   // 2*2048*16*32 = 2,097,152
  const int i = idx & 31;
  const int h = (idx >> 5) & 15;
  const int n = idx >> 9;
  const float pos = (float)((n & 2047) + posoff[0]);
  const float ang = pos * __expf(-0.2878231366f * (float)i);   // ln(10000)/32
  float sn, cs;
  __sincosf(ang, &sn, &cs);
  size_t base = (size_t)n*3072 + h*64 + i;
  {
    float x1 = __bfloat162float(qkv[base]);
    float x2 = __bfloat162float(qkv[base + 32]);
    qkv[base]      = __float2bfloat16((x1*cs - x2*sn) * 0.125f);
    qkv[base + 32] = __float2bfloat16((x1*sn + x2*cs) * 0.125f);
  }
  {
    float x1 = __bfloat162float(qkv[base + 1024]);
    float x2 = __bfloat162float(qkv[base + 1056]);
    qkv[base + 1024] = __float2bfloat16(x1*cs - x2*sn);
    qkv[base + 1056] = __float2bfloat16(x1*sn + x2*cs);
  }
}

// ---------------- flash attention (causal), 64-q x 64-k tiles, 4 waves ----------------
// Balanced pairing: block x=i handles qt=i then qt=31-i (33 k-tiles each, no tail).
// T14 async-stage: K/V for tile kt+1 loaded to regs during tile kt's compute.
__global__ __launch_bounds__(256) void attn_kernel(const bf16* __restrict__ qkv, bf16* __restrict__ o){
  const int bh = blockIdx.y;
  const int b = bh >> 4, h = bh & 15;
  const int tid = threadIdx.x, lane = tid & 63, wave = tid >> 6;
  const int lr = lane & 15, lg = lane >> 4;
  __shared__ __align__(16) bf16 Kt[64*72];      // K tile row-major, padded stride 72
  __shared__ __align__(16) bf16 Vt[64*72];      // V^T tile: Vt[d][kj]
  __shared__ __align__(16) bf16 P[4][16*72];    // per-wave P, padded

  const size_t bbase = (size_t)b*2048*3072;

  bf16x8 kreg[2];
  bf16 vreg[16];

  auto loadKV = [&](int kt){
    #pragma unroll
    for (int i=0;i<2;i++){
      int ch = i*256 + tid;
      int r = ch >> 3, c = ch & 7;
      kreg[i] = *reinterpret_cast<const bf16x8*>(&qkv[bbase + (size_t)(kt*64+r)*3072 + 1024 + h*64 + c*8]);
    }
    #pragma unroll
    for (int i=0;i<16;i++){
      int idx = i*256 + tid;
      int r = idx >> 6, d = idx & 63;
      vreg[i] = qkv[bbase + (size_t)(kt*64+r)*3072 + 2048 + h*64 + d];
    }
  };
  auto writeKV = [&](){
    #pragma unroll
    for (int i=0;i<2;i++){
      int ch = i*256 + tid;
      int r = ch >> 3, c = ch & 7;
      *reinterpret_cast<bf16x8*>(&Kt[r*72 + c*8]) = kreg[i];
    }
    #pragma unroll
    for (int i=0;i<16;i++){
      int idx = i*256 + tid;
      int r = idx >> 6, d = idx & 63;
      Vt[d*72 + r] = vreg[i];
    }
  };

  #pragma unroll 1
  for (int half=0; half<2; half++){
    const int qt = (half == 0) ? (int)blockIdx.x : 31 - (int)blockIdx.x;
    const int qrow = qt*64 + wave*16 + lr;
    bf16x8 qf[2];
    #pragma unroll
    for (int kk=0;kk<2;kk++)
      qf[kk] = *reinterpret_cast<const bf16x8*>(&qkv[bbase + (size_t)qrow*3072 + h*64 + kk*32 + lg*8]);

    f32x4 oacc[4];
    #pragma unroll
    for (int ni=0;ni<4;ni++) oacc[ni] = (f32x4){0.f,0.f,0.f,0.f};
    float mrow[4] = {-1e30f,-1e30f,-1e30f,-1e30f};
    float srow[4] = {0.f,0.f,0.f,0.f};

    loadKV(0);

    #pragma unroll 1
    for (int kt=0; kt<=qt; kt++){
      __syncthreads();
      writeKV();
      __syncthreads();
      if (kt < qt) loadKV(kt+1);      // T14: in flight during compute below

      f32x4 sacc[4];
      #pragma unroll
      for (int ni=0;ni<4;ni++) sacc[ni] = (f32x4){0.f,0.f,0.f,0.f};
      __builtin_amdgcn_s_setprio(1);
      #pragma unroll
      for (int kk=0;kk<2;kk++)
        #pragma unroll
        for (int ni=0;ni<4;ni++){
          bf16x8 kb = *reinterpret_cast<const bf16x8*>(&Kt[(ni*16+lr)*72 + kk*32 + lg*8]);
          sacc[ni] = __builtin_amdgcn_mfma_f32_16x16x32_bf16(qf[kk], kb, sacc[ni], 0,0,0);
        }
      __builtin_amdgcn_s_setprio(0);
      if (kt == qt){
        #pragma unroll
        for (int ni=0;ni<4;ni++)
          #pragma unroll
          for (int j=0;j<4;j++)
            if (ni*16 + lr > wave*16 + lg*4 + j) sacc[ni][j] = -1e30f;
      }
      float pm[4];
      #pragma unroll
      for (int j=0;j<4;j++)
        pm[j] = fmaxf(fmaxf(sacc[0][j], sacc[1][j]), fmaxf(sacc[2][j], sacc[3][j]));
      #pragma unroll
      for (int off=1; off<16; off<<=1)
        #pragma unroll
        for (int j=0;j<4;j++) pm[j] = fmaxf(pm[j], __shfl_xor(pm[j], off));
      float sc[4], rs[4];
      #pragma unroll
      for (int j=0;j<4;j++){
        float mn = fmaxf(mrow[j], pm[j]);
        sc[j] = __expf(mrow[j] - mn);
        mrow[j] = mn;
        rs[j] = 0.f;
      }
      #pragma unroll
      for (int ni=0;ni<4;ni++)
        #pragma unroll
        for (int j=0;j<4;j++){
          float p = __expf(sacc[ni][j] - mrow[j]);
          sacc[ni][j] = p;
          rs[j] += p;
        }
      #pragma unroll
      for (int off=1; off<16; off<<=1)
        #pragma unroll
        for (int j=0;j<4;j++) rs[j] += __shfl_xor(rs[j], off);
      #pragma unroll
      for (int j=0;j<4;j++) srow[j] = srow[j]*sc[j] + rs[j];
      #pragma unroll
      for (int ni=0;ni<4;ni++)
        #pragma unroll
        for (int j=0;j<4;j++)
          P[wave][(lg*4+j)*72 + ni*16 + lr] = __float2bfloat16(sacc[ni][j]);
      #pragma unroll
      for (int ni=0;ni<4;ni++)
        #pragma unroll
        for (int j=0;j<4;j++) oacc[ni][j] *= sc[j];
      asm volatile("s_waitcnt lgkmcnt(0)" ::: "memory");
      __builtin_amdgcn_sched_barrier(0);
      bf16x8 pa0 = *reinterpret_cast<const bf16x8*>(&P[wave][lr*72 + lg*8]);
      bf16x8 pa1 = *reinterpret_cast<const bf16x8*>(&P[wave][lr*72 + 32 + lg*8]);
      __builtin_amdgcn_s_setprio(1);
      #pragma unroll
      for (int ni=0;ni<4;ni++){
        bf16x8 vb0 = *reinterpret_cast<const bf16x8*>(&Vt[(ni*16+lr)*72 + lg*8]);
        oacc[ni] = __builtin_amdgcn_mfma_f32_16x16x32_bf16(pa0, vb0, oacc[ni], 0,0,0);
        bf16x8 vb1 = *reinterpret_cast<const bf16x8*>(&Vt[(ni*16+lr)*72 + 32 + lg*8]);
        oacc[ni] = __builtin_amdgcn_mfma_f32_16x16x32_bf16(pa1, vb1, oacc[ni], 0,0,0);
      }
      __builtin_amdgcn_s_setprio(0);
    }
    #pragma unroll
    for (int ni=0;ni<4;ni++)
      #pragma unroll
      for (int j=0;j<4;j++){
        int row = qt*64 + wave*16 + lg*4 + j;
        int col = h*64 + ni*16 + lr;
        o[(size_t)(b*2048 + row)*1024 + col] = __float2bfloat16(oacc[ni][j] / srow[j]);
      }
  }
}

// ---------------- final reduce: out = x_res + sum_s partial + sum_e gate*eout_b ----------------
__global__ __launch_bounds__(256) void reduce_out_kernel(const float* __restrict__ partial, const float* __restrict__ xres,
    const float* __restrict__ gate, const float* __restrict__ eob, float* __restrict__ out){
  const int idx = blockIdx.x*256 + threadIdx.x;   // float4 index, 1,048,576 total
  float4 v = reinterpret_cast<const float4*>(xres)[idx];
  #pragma unroll
  for (int s=0;s<4;s++){
    float4 p = reinterpret_cast<const float4*>(partial + (size_t)s*4194304)[idx];
    v.x += p.x; v.y += p.y; v.z += p.z; v.w += p.w;
  }
  const int n = idx >> 8;
  const int c = (idx << 2) & 1023;
  #pragma unroll
  for (int e=0;e<8;e++){
    const float gp = gate[n*8+e];
    const float4 eb = *reinterpret_cast<const float4*>(&eob[e*1024 + c]);
    v.x += gp*eb.x; v.y += gp*eb.y; v.z += gp*eb.z; v.w += gp*eb.w;
  }
  reinterpret_cast<float4*>(out)[idx] = v;
}

__global__ __launch_bounds__(256) void util_kernel(const float* __restrict__ gate, float* __restrict__ outloss){
  const int tid = threadIdx.x, lane = tid & 63, wave = tid >> 6;
  float p[8] = {0,0,0,0,0,0,0,0};
  for (int r = tid; r < 4096; r += 256)
    #pragma unroll
    for (int e=0;e<8;e++) p[e] += gate[r*8+e];
  #pragma unroll
  for (int off=1; off<64; off<<=1)
    #pragma unroll
    for (int e=0;e<8;e++) p[e] += __shfl_xor(p[e], off);
  __shared__ float rb[4][8];
  if (lane == 0)
    #pragma unroll
    for (int e=0;e<8;e++) rb[wave][e] = p[e];
  __syncthreads();
  if (tid == 0){
    float loss = 0.f;
    #pragma unroll
    for (int e=0;e<8;e++){
      float u = (rb[0][e]+rb[1][e]+rb[2][e]+rb[3][e]) * (1.f/4096.f) - 0.125f;
      loss += u*u;
    }
    outloss[0] = loss;
  }
}

extern "C" void kernel_launch(void* const* d_in, const int* in_sizes, int n_in,
                              void* d_out, int out_size, void* d_ws, size_t ws_size,
                              hipStream_t stream){
  const float* x    = (const float*)d_in[0];
  const int*   poff = (const int*)  d_in[2];
  const float* ln1g = (const float*)d_in[3];
  const float* ln1b = (const float*)d_in[4];
  const float* qkvw = (const float*)d_in[5];
  const float* qkvb = (const float*)d_in[6];
  const float* aow  = (const float*)d_in[7];
  const float* aob  = (const float*)d_in[8];
  const float* ln2g = (const float*)d_in[9];
  const float* ln2b = (const float*)d_in[10];
  const float* gw   = (const float*)d_in[11];
  const float* gb   = (const float*)d_in[12];
  const float* fcw  = (const float*)d_in[13];
  const float* fcb  = (const float*)d_in[14];
  const float* eow  = (const float*)d_in[15];
  const float* eob  = (const float*)d_in[16];
  float* out = (float*)d_out;
  char* ws = (char*)d_ws;

  if (ws_size < 260308992ull) return;  // layout below needs ~248 MB

  bf16*  WqkvT  = (bf16*)(ws + 0);          //  6.3 MB
  bf16*  WattnT = (bf16*)(ws + 6291456);    //  2.1 MB
  bf16*  h1     = (bf16*)(ws + 8388608);    //  8.4 MB
  bf16*  qkv    = (bf16*)(ws + 16777216);   // 25.2 MB
  bf16*  o      = (bf16*)(ws + 41943040);   //  8.4 MB
  bf16*  act    = (bf16*)(ws + 0);          // 134 MB (overwrites the 5 above)
  bf16*  WfcT   = (bf16*)(ws + 134217728);  // 67 MB
  float* partial= (float*)(ws + 134217728); // 64 MB (overwrites WfcT after fc GEMM)
  bf16*  WeoutT = (bf16*)(ws + 201326592);  // 33.6 MB
  float* biasFc = (float*)(ws + 234881024);
  float* xres   = (float*)(ws + 235012096); // 16.8 MB
  bf16*  h2     = (bf16*)(ws + 251789312);  //  8.4 MB
  float* gate   = (float*)(ws + 260177920);

  packT_kernel<<<dim3(96,32), 256, 0, stream>>>(qkvw, WqkvT, 1024, 3072);
  packT_kernel<<<dim3(32,32), 256, 0, stream>>>(aow, WattnT, 1024, 1024);
  pack_fc_kernel<<<dim3(128,32,8), 256, 0, stream>>>(fcw, WfcT);
  pack_eout_kernel<<<dim3(64,32,8), 256, 0, stream>>>(eow, WeoutT);
  pack_biasfc_kernel<<<128, 256, 0, stream>>>(fcb, biasFc);

  ln1_kernel<<<4096, 256, 0, stream>>>(x, ln1g, ln1b, h1);
  gemm_bt<0><<<dim3(24,32), 256, 0, stream>>>(h1, WqkvT, 3072, 1024, 1024, qkv, nullptr, qkvb, nullptr, nullptr);
  rope_kernel<<<8192, 256, 0, stream>>>(qkv, poff);
  attn_kernel<<<dim3(16,32), 256, 0, stream>>>(qkv, o);
  gemm_bt<1><<<dim3(8,32), 256, 0, stream>>>(o, WattnT, 1024, 1024, 1024, nullptr, xres, aob, x, nullptr);
  ln2gate_kernel<<<4096, 256, 0, stream>>>(xres, ln2g, ln2b, gw, gb, h2, gate);
  gemm256<2><<<dim3(128,16), 512, 0, stream>>>(h2, WfcT, 1024, 1024, act, nullptr, biasFc, gate);
  gemm256<4><<<dim3(4,16,4), 512, 0, stream>>>(act, WeoutT, 16384, 4096, nullptr, partial, nullptr, nullptr);
  reduce_out_kernel<<<4096, 256, 0, stream>>>(partial, xres, gate, eob, out);
  util_kernel<<<1, 256, 0, stream>>>(gate, out + 4194304);
}